// Round 3
// baseline (138.645 us; speedup 1.0000x reference)
//
#include <hip/hip_runtime.h>
#include <hip/hip_fp16.h>

#define Bq 16
#define Nq 2048
#define Sq 4096
#define Dq 128
#define VOCABq 50257
#define NNZq 1048576
#define ROWS (Bq * Nq)   // 32768
#define NBIN 512         // bins of 64 rows
#define RPB 64           // rows per bin
#define BTPB 512         // bin kernel threads
#define BEPT 4           // bin entries/thread
#define ENT (BTPB * BEPT)       // 2048 entries per bin block
#define NBBLK (NNZq / ENT)      // 512 bin blocks
#define PTPB 1024        // pool threads (64 row-groups x 16 lanes)
#define NKEY 256         // pool sort keys: 4 token-quarters x 64 rows
#define EBUF 2560        // pool entry buffer (mean 2048, sd ~45 -> +11 sigma)

typedef unsigned long long u64;
typedef u64 u64x2 __attribute__((ext_vector_type(2)));
typedef float vfloat4 __attribute__((ext_vector_type(4)));
typedef unsigned short vushort4 __attribute__((ext_vector_type(4)));
typedef unsigned short vushort8 __attribute__((ext_vector_type(8)));

// ---------- Pass 0: cast emb table fp32 -> fp16 (rows 512B -> 256B) ----------
__global__ __launch_bounds__(256) void cast_kernel(
    const float* __restrict__ emb, unsigned short* __restrict__ emb16)
{
    const int NQUAD = (VOCABq * Dq) / 4;  // 1,608,224
    int i = blockIdx.x * 256 + threadIdx.x;
    if (i >= NQUAD) return;
    vfloat4 f = reinterpret_cast<const vfloat4*>(emb)[i];
    vushort4 h;
    h.x = __half_as_ushort(__float2half_rn(f.x));
    h.y = __half_as_ushort(__float2half_rn(f.y));
    h.z = __half_as_ushort(__float2half_rn(f.z));
    h.w = __half_as_ushort(__float2half_rn(f.w));
    __builtin_nontemporal_store(h, reinterpret_cast<vushort4*>(emb16) + i);
}

// ---------- Pass A: per-block bin sort -> private contiguous segment ----------
// Each block sorts its 2048 entries by bin (9-bit) in LDS and writes the whole
// sorted blob to its OWN segment binMem[block][0..ENT) with offsets in
// offTab[block][bin]. No global atomics, no overflow, fully coalesced
// vectorized stores.
__global__ __launch_bounds__(BTPB) void bin_kernel(
    const int* __restrict__ subnode_ids,   // [B,S]
    const int* __restrict__ mb,            // [NNZ]
    const int* __restrict__ mn,            // [NNZ]
    const int* __restrict__ ms,            // [NNZ]
    const float* __restrict__ mv,          // [NNZ]
    u64* __restrict__ binMem,              // [NBBLK][ENT] sorted-by-bin blobs
    int* __restrict__ offTab)              // [NBBLK][NBIN] slice starts
{
    __shared__ int hist[NBIN];     // per-block bin counts (BTPB == NBIN)
    __shared__ int lstart[NBIN];   // local exclusive prefix
    __shared__ int waveSum[BTPB / 64];
    __shared__ u64 spk[ENT] __attribute__((aligned(16)));  // 16 KB sorted entries

    int t = threadIdx.x;
    hist[t] = 0;                   // BTPB == NBIN: one bin per thread
    __syncthreads();

    int blockBase = blockIdx.x * ENT;
    int g[BEPT], rank[BEPT];
    u64 pk[BEPT];
    #pragma unroll
    for (int k = 0; k < BEPT; k++) {       // coalesced NT index loads + L2 token gather
        int i   = blockBase + k * BTPB + t;
        int b   = __builtin_nontemporal_load(mb + i);
        int row = b * Nq + __builtin_nontemporal_load(mn + i);
        int s   = __builtin_nontemporal_load(ms + i);
        float v = __builtin_nontemporal_load(mv + i);
        int tok = subnode_ids[b * Sq + s];
        g[k]  = row >> 6;                  // bin of 64 rows
        pk[k] = ((u64)(unsigned)__float_as_int(v) << 32)
              | ((u64)(row & 63) << 16)
              | (unsigned)tok;             // tok < 65536 fits 16 bits
        rank[k] = atomicAdd(&hist[g[k]], 1);
    }
    __syncthreads();

    // exclusive prefix over 512 bins (8 waves + cross-wave fixup)
    int lane = t & 63, wid = t >> 6;
    int v  = hist[t];
    int vi = v;
    #pragma unroll
    for (int d = 1; d < 64; d <<= 1) {
        int w = __shfl_up(vi, d, 64);
        if (lane >= d) vi += w;
    }
    if (lane == 63) waveSum[wid] = vi;
    __syncthreads();
    if (t == 0) {
        int s = 0;
        #pragma unroll
        for (int w = 0; w < BTPB / 64; w++) { int x = waveSum[w]; waveSum[w] = s; s += x; }
    }
    __syncthreads();
    int ex = vi - v + waveSum[wid];
    lstart[t] = ex;
    offTab[blockIdx.x * NBIN + t] = ex;    // coalesced 2KB offset row
    __syncthreads();

    // scatter into LDS sorted by (bin, rank)
    #pragma unroll
    for (int k = 0; k < BEPT; k++)
        spk[lstart[g[k]] + rank[k]] = pk[k];
    __syncthreads();

    // contiguous vectorized write-out of the sorted blob (16B stores)
    const u64x2* s2 = reinterpret_cast<const u64x2*>(spk);
    u64x2* d2 = reinterpret_cast<u64x2*>(binMem + (size_t)blockIdx.x * ENT);
    #pragma unroll
    for (int p = t; p < ENT / 2; p += BTPB)
        d2[p] = s2[p];
}

// ---------- Pass B: gather slices -> in-LDS sort by (quarter,row) -> pool ----------
// One 1024-thread block per bin (64 rows). Pass 1 reads the bin's 512 slices
// (one per bin block) and histograms 256 keys; pass 2 re-reads (L1-hot) and
// scatters into ebuf sorted by key = (tok>>14)<<6 | row_local. Then 4
// token-quarter phases (~3.2MB fp16 table slice L2-resident); 64 groups of 16
// lanes, group g owns row g; acc in fp32 regs; one NT 512B store per row.
__global__ __launch_bounds__(PTPB) void pool_kernel(
    const unsigned short* __restrict__ emb16,  // [VOCAB,D] fp16
    const u64* __restrict__ binMem,            // [NBBLK][ENT]
    const int* __restrict__ offTab,            // [NBBLK][NBIN]
    float* __restrict__ out)                   // [ROWS,D]
{
    __shared__ u64 ebuf[EBUF];          // 20 KB sorted entries
    __shared__ int hist[NKEY];
    __shared__ int start[NKEY + 1];
    __shared__ int cursor[NKEY];
    __shared__ int waveSum[NKEY / 64];
    __shared__ int sstart[NBBLK];
    __shared__ int scnt[NBBLK];

    int t   = threadIdx.x;
    int bin = blockIdx.x;
    if (t < NKEY) hist[t] = 0;
    __syncthreads();

    // pass 1: slice bounds + histogram
    if (t < NBBLK) {
        int s0 = offTab[t * NBIN + bin];
        int s1 = (bin == NBIN - 1) ? ENT : offTab[t * NBIN + bin + 1];
        sstart[t] = s0;
        scnt[t]   = s1 - s0;
        const u64* src = binMem + (size_t)t * ENT;
        for (int e = s0; e < s1; e++) {
            u64 pk  = src[e];
            int tok = (int)(pk & 0xFFFF);
            int key = ((tok >> 14) << 6) | (int)((pk >> 16) & 63);
            atomicAdd(&hist[key], 1);
        }
    }
    __syncthreads();

    // exclusive prefix over 256 keys (4 waves + cross-wave fixup)
    int lane = t & 63, wid = t >> 6;
    int v  = (t < NKEY) ? hist[t] : 0;
    int vi = v;
    #pragma unroll
    for (int d = 1; d < 64; d <<= 1) {
        int w = __shfl_up(vi, d, 64);
        if (lane >= d) vi += w;
    }
    if (t < NKEY && lane == 63) waveSum[wid] = vi;
    __syncthreads();
    if (t == 0) {
        int s = 0;
        #pragma unroll
        for (int w = 0; w < NKEY / 64; w++) { int x = waveSum[w]; waveSum[w] = s; s += x; }
    }
    __syncthreads();
    if (t < NKEY) {
        int ex = vi - v + waveSum[wid];
        start[t]  = ex;
        cursor[t] = ex;
        if (t == NKEY - 1) start[NKEY] = ex + v;
    }
    __syncthreads();

    // pass 2: scatter (slice re-read is L1-hot)
    if (t < NBBLK) {
        const u64* src = binMem + (size_t)t * ENT + sstart[t];
        int c = scnt[t];
        for (int e = 0; e < c; e++) {
            u64 pk  = src[e];
            int tok = (int)(pk & 0xFFFF);
            int key = ((tok >> 14) << 6) | (int)((pk >> 16) & 63);
            int p = atomicAdd(&cursor[key], 1);
            if (p < EBUF) ebuf[p] = pk;
        }
    }
    __syncthreads();

    // pool: group g (16 lanes) owns row g; 4 token-quarter phases
    int g      = t >> 4;       // 0..63
    int lane16 = t & 15;
    vfloat4 a0 = {0.f, 0.f, 0.f, 0.f};
    vfloat4 a1 = {0.f, 0.f, 0.f, 0.f};
    #pragma unroll
    for (int q = 0; q < 4; q++) {
        int s0 = min(start[q * 64 + g], EBUF);
        int s1 = min(start[q * 64 + g + 1], EBUF);
        int k = s0;
        for (; k + 8 <= s1; k += 8) {      // 8 independent 256B row-gathers in flight
            int   tk[8];
            float vv[8];
            #pragma unroll
            for (int u = 0; u < 8; u++) {
                u64 pk = ebuf[k + u];      // same addr within group -> broadcast
                tk[u] = (int)(pk & 0xFFFF);
                vv[u] = __int_as_float((int)(pk >> 32));
            }
            vushort8 e[8];
            #pragma unroll
            for (int u = 0; u < 8; u++)
                e[u] = reinterpret_cast<const vushort8*>(emb16 + (size_t)tk[u] * Dq)[lane16];
            #pragma unroll
            for (int u = 0; u < 8; u++) {
                a0.x += __half2float(__ushort_as_half(e[u][0])) * vv[u];
                a0.y += __half2float(__ushort_as_half(e[u][1])) * vv[u];
                a0.z += __half2float(__ushort_as_half(e[u][2])) * vv[u];
                a0.w += __half2float(__ushort_as_half(e[u][3])) * vv[u];
                a1.x += __half2float(__ushort_as_half(e[u][4])) * vv[u];
                a1.y += __half2float(__ushort_as_half(e[u][5])) * vv[u];
                a1.z += __half2float(__ushort_as_half(e[u][6])) * vv[u];
                a1.w += __half2float(__ushort_as_half(e[u][7])) * vv[u];
            }
        }
        for (; k < s1; k++) {
            u64 pk = ebuf[k];
            int   tok = (int)(pk & 0xFFFF);
            float v2  = __int_as_float((int)(pk >> 32));
            vushort8 e = reinterpret_cast<const vushort8*>(emb16 + (size_t)tok * Dq)[lane16];
            a0.x += __half2float(__ushort_as_half(e[0])) * v2;
            a0.y += __half2float(__ushort_as_half(e[1])) * v2;
            a0.z += __half2float(__ushort_as_half(e[2])) * v2;
            a0.w += __half2float(__ushort_as_half(e[3])) * v2;
            a1.x += __half2float(__ushort_as_half(e[4])) * v2;
            a1.y += __half2float(__ushort_as_half(e[5])) * v2;
            a1.z += __half2float(__ushort_as_half(e[6])) * v2;
            a1.w += __half2float(__ushort_as_half(e[7])) * v2;
        }
    }

    float* orow = out + ((size_t)bin * RPB + g) * Dq + lane16 * 8;
    __builtin_nontemporal_store(a0, reinterpret_cast<vfloat4*>(orow));
    __builtin_nontemporal_store(a1, reinterpret_cast<vfloat4*>(orow) + 1);
}

extern "C" void kernel_launch(void* const* d_in, const int* in_sizes, int n_in,
                              void* d_out, int out_size, void* d_ws, size_t ws_size,
                              hipStream_t stream) {
    const int*   subnode_ids  = (const int*)d_in[0];
    const int*   mask_batch   = (const int*)d_in[1];
    const int*   mask_node    = (const int*)d_in[2];
    const int*   mask_subnode = (const int*)d_in[3];
    const float* mask_values  = (const float*)d_in[4];
    const float* emb_table    = (const float*)d_in[5];
    float*       out          = (float*)d_out;

    // ws layout: emb16[VOCAB*D halves, 12.86 MB] | binMem[NBBLK*ENT u64, 8 MB]
    //          | offTab[NBBLK*NBIN int, 4 MB]
    unsigned short* emb16 = (unsigned short*)d_ws;
    u64* binMem = (u64*)(emb16 + (size_t)VOCABq * Dq + 64 /*align pad*/);
    int* offTab = (int*)(binMem + (size_t)NBBLK * ENT);

    const int NQUAD = (VOCABq * Dq) / 4;
    cast_kernel<<<(NQUAD + 255) / 256, 256, 0, stream>>>(emb_table, emb16);
    bin_kernel<<<NBBLK, BTPB, 0, stream>>>(
        subnode_ids, mask_batch, mask_node, mask_subnode, mask_values,
        binMem, offTab);
    pool_kernel<<<NBIN, PTPB, 0, stream>>>(emb16, binMem, offTab, out);
}

// Round 6
// 135.840 us; speedup vs baseline: 1.0206x; 1.0206x over previous
//
#include <hip/hip_runtime.h>
#include <hip/hip_fp16.h>

#define Bq 16
#define Nq 2048
#define Sq 4096
#define Dq 128
#define VOCABq 50257
#define NNZq 1048576
#define ROWS (Bq * Nq)   // 32768
#define NBIN 512         // bins of 64 rows; == NBLK == TPB (load-balance alignment)
#define RPB 64           // rows per bin
#define TPB 512          // threads per block (both kernels)
#define BEPT 4           // bin entries per thread
#define ENT (TPB * BEPT)        // 2048 entries per bin-block
#define NBLK (NNZq / ENT)       // 512 bin blocks
#define NKEY 256         // pool sort keys: 4 token-quarters x 64 rows
#define EBUF 2560        // per-bin entry cap (mean 2048, sd ~45 -> +11 sigma)
#define NQUAD ((VOCABq * Dq) / 4)   // 1,608,224

typedef unsigned long long u64;
typedef u64 u64x2 __attribute__((ext_vector_type(2)));
typedef float vfloat4 __attribute__((ext_vector_type(4)));
typedef unsigned short vushort4 __attribute__((ext_vector_type(4)));
typedef unsigned short vushort8 __attribute__((ext_vector_type(8)));

// exclusive prefix over TPB values (one per thread); uses waveSum[TPB/64]
__device__ __forceinline__ int scan_block(int val, int t, int* waveSum) {
    int lane = t & 63, wid = t >> 6;
    int vi = val;
    #pragma unroll
    for (int d = 1; d < 64; d <<= 1) {
        int w = __shfl_up(vi, d, 64);
        if (lane >= d) vi += w;
    }
    if (lane == 63) waveSum[wid] = vi;
    __syncthreads();
    if (t == 0) {
        int s = 0;
        #pragma unroll
        for (int w = 0; w < TPB / 64; w++) { int x = waveSum[w]; waveSum[w] = s; s += x; }
    }
    __syncthreads();
    return vi - val + waveSum[wid];
}

// accumulate ebuf[s0..s1) (16-lane group, lane16 owns a 16B ushort8 slice)
__device__ __forceinline__ void accum_range(
    const u64* ebuf, int s0, int s1, int lane16,
    const unsigned short* __restrict__ emb16, vfloat4& A0, vfloat4& A1)
{
    int k = s0;
    for (; k + 8 <= s1; k += 8) {          // 8 independent 256B row-gathers in flight
        int tk[8]; float vv[8];
        #pragma unroll
        for (int u = 0; u < 8; u++) {
            u64 pk = ebuf[k + u];          // same addr within group -> broadcast
            tk[u] = (int)(pk & 0xFFFF);
            vv[u] = __int_as_float((int)(pk >> 32));
        }
        vushort8 e[8];
        #pragma unroll
        for (int u = 0; u < 8; u++)
            e[u] = reinterpret_cast<const vushort8*>(emb16 + (size_t)tk[u] * Dq)[lane16];
        #pragma unroll
        for (int u = 0; u < 8; u++) {
            A0.x += __half2float(__ushort_as_half(e[u][0])) * vv[u];
            A0.y += __half2float(__ushort_as_half(e[u][1])) * vv[u];
            A0.z += __half2float(__ushort_as_half(e[u][2])) * vv[u];
            A0.w += __half2float(__ushort_as_half(e[u][3])) * vv[u];
            A1.x += __half2float(__ushort_as_half(e[u][4])) * vv[u];
            A1.y += __half2float(__ushort_as_half(e[u][5])) * vv[u];
            A1.z += __half2float(__ushort_as_half(e[u][6])) * vv[u];
            A1.w += __half2float(__ushort_as_half(e[u][7])) * vv[u];
        }
    }
    for (; k < s1; k++) {
        u64 pk = ebuf[k];
        int   tok = (int)(pk & 0xFFFF);
        float v2  = __int_as_float((int)(pk >> 32));
        vushort8 e = reinterpret_cast<const vushort8*>(emb16 + (size_t)tok * Dq)[lane16];
        A0.x += __half2float(__ushort_as_half(e[0])) * v2;
        A0.y += __half2float(__ushort_as_half(e[1])) * v2;
        A0.z += __half2float(__ushort_as_half(e[2])) * v2;
        A0.w += __half2float(__ushort_as_half(e[3])) * v2;
        A1.x += __half2float(__ushort_as_half(e[4])) * v2;
        A1.y += __half2float(__ushort_as_half(e[5])) * v2;
        A1.z += __half2float(__ushort_as_half(e[6])) * v2;
        A1.w += __half2float(__ushort_as_half(e[7])) * v2;
    }
}

// ---------- Pass 0: cast emb table fp32 -> fp16 (rows 512B -> 256B) ----------
__global__ __launch_bounds__(256) void cast_kernel(
    const float* __restrict__ emb, unsigned short* __restrict__ emb16)
{
    int i = blockIdx.x * 256 + threadIdx.x;
    if (i >= NQUAD) return;
    vfloat4 f = reinterpret_cast<const vfloat4*>(emb)[i];
    vushort4 h;
    h.x = __half_as_ushort(__float2half_rn(f.x));
    h.y = __half_as_ushort(__float2half_rn(f.y));
    h.z = __half_as_ushort(__float2half_rn(f.z));
    h.w = __half_as_ushort(__float2half_rn(f.w));
    __builtin_nontemporal_store(h, reinterpret_cast<vushort4*>(emb16) + i);
}

// ---------- Pass A: per-block bin sort -> private contiguous segment ----------
// Each block sorts its 2048 entries by 9-bit bin in LDS, writes the sorted blob
// to its OWN segment binMem[blk][0..ENT) + packed off|cnt<<16 table. No global
// atomics, no overflow path, fully coalesced vectorized stores.
__global__ __launch_bounds__(TPB) void bin_kernel(
    const int* __restrict__ subnode_ids,   // [B,S]
    const int* __restrict__ mb,            // [NNZ]
    const int* __restrict__ mn,            // [NNZ]
    const int* __restrict__ ms,            // [NNZ]
    const float* __restrict__ mv,          // [NNZ]
    u64* __restrict__ binMem,              // [NBLK][ENT] sorted-by-bin blobs
    unsigned* __restrict__ offTab)         // [NBLK][NBIN] off | cnt<<16
{
    __shared__ int hist[NBIN];             // 2 KB  (TPB == NBIN: one bin/thread)
    __shared__ int lstart[NBIN];           // 2 KB
    __shared__ int waveSum[TPB / 64];
    __shared__ u64 spk[ENT] __attribute__((aligned(16)));   // 16 KB sorted entries

    int t   = threadIdx.x;
    int blk = blockIdx.x;

    hist[t] = 0;
    __syncthreads();

    int base = blk * ENT;
    int g[BEPT], rank[BEPT];
    u64 pk[BEPT];
    #pragma unroll
    for (int k = 0; k < BEPT; k++) {       // coalesced NT index loads + L2 token gather
        int i   = base + k * TPB + t;
        int b   = __builtin_nontemporal_load(mb + i);
        int row = b * Nq + __builtin_nontemporal_load(mn + i);
        int s   = __builtin_nontemporal_load(ms + i);
        float v = __builtin_nontemporal_load(mv + i);
        int tok = subnode_ids[b * Sq + s];
        g[k]  = row >> 6;                  // bin of 64 rows
        pk[k] = ((u64)(unsigned)__float_as_int(v) << 32)
              | ((u64)(row & 63) << 16)
              | (unsigned)tok;             // tok < 65536 fits 16 bits
        rank[k] = atomicAdd(&hist[g[k]], 1);
    }
    __syncthreads();

    int cnt = hist[t];
    int ex  = scan_block(cnt, t, waveSum);
    lstart[t] = ex;
    offTab[blk * NBIN + t] = (unsigned)ex | ((unsigned)cnt << 16);  // coalesced
    __syncthreads();

    #pragma unroll
    for (int k = 0; k < BEPT; k++)
        spk[lstart[g[k]] + rank[k]] = pk[k];
    __syncthreads();

    // contiguous vectorized blob write-out (16B stores)
    const u64x2* s2 = reinterpret_cast<const u64x2*>(spk);
    u64x2* d2 = reinterpret_cast<u64x2*>(binMem + (size_t)blk * ENT);
    #pragma unroll
    for (int p = t; p < ENT / 2; p += TPB) d2[p] = s2[p];
}

// ---------- Pass B: gather slices -> in-LDS key sort -> phased pool ----------
// Block b = bin b (64 rows). All 512 threads: thread t copies the slice from
// producer block t into spk (positions from a block scan) -> single global
// read pass, then LDS-only 256-key histogram/scan/scatter into ebuf sorted by
// key = (tok>>14)<<6 | row_local. 32 groups x 16 lanes; group g owns rows g
// and g+32 (8 fp32 acc regs/thread); 4 token-quarter phases (~3.2MB fp16
// table slice L2-resident across co-resident blocks); one NT 512B store/row.
__global__ __launch_bounds__(TPB) void pool_kernel(
    const unsigned short* __restrict__ emb16,  // [VOCAB,D] fp16
    const u64* __restrict__ binMem,            // [NBLK][ENT]
    const unsigned* __restrict__ offTab,       // [NBLK][NBIN] off | cnt<<16
    float* __restrict__ out)                   // [ROWS,D]
{
    __shared__ u64 spk[EBUF] __attribute__((aligned(16)));   // 20 KB staged
    __shared__ u64 ebuf[EBUF];             // 20 KB key-sorted entries
    __shared__ int waveSum[TPB / 64];
    __shared__ int khist[NKEY];            // 1 KB
    __shared__ int kstart[NKEY + 1];
    __shared__ int kcursor[NKEY];
    __shared__ int nTot;

    int t   = threadIdx.x;
    int bin = blockIdx.x;

    // slice meta: thread t owns the slice from producer block t (TPB == NBLK)
    unsigned m = offTab[t * NBIN + bin];
    int soff = (int)(m & 0xFFFFu);
    int scnt = (int)(m >> 16);
    int db   = scan_block(scnt, t, waveSum);
    if (t == TPB - 1) nTot = db + scnt;
    if (db >= EBUF) scnt = 0;
    else if (db + scnt > EBUF) scnt = EBUF - db;     // paranoia clamp

    // cooperative slice copy: each slice is a contiguous run in its segment
    {
        const u64* src = binMem + (size_t)t * ENT + soff;
        for (int i = 0; i < scnt; i++) spk[db + i] = src[i];
    }
    if (t < NKEY) khist[t] = 0;
    __syncthreads();

    int n = nTot < EBUF ? nTot : EBUF;

    // 256-key histogram from staged LDS
    for (int e = t; e < n; e += TPB) {
        u64 p = spk[e];
        int key = (((int)(p & 0xFFFF)) >> 14 << 6) | ((int)(p >> 16) & 63);
        atomicAdd(&khist[key], 1);
    }
    __syncthreads();

    int kval = (t < NKEY) ? khist[t] : 0;
    int kex  = scan_block(kval, t, waveSum);
    if (t < NKEY) {
        kstart[t]  = kex;
        kcursor[t] = kex;
        if (t == NKEY - 1) kstart[NKEY] = kex + kval;
    }
    __syncthreads();

    // scatter into key-sorted ebuf
    for (int e = t; e < n; e += TPB) {
        u64 p = spk[e];
        int key = (((int)(p & 0xFFFF)) >> 14 << 6) | ((int)(p >> 16) & 63);
        int pos = atomicAdd(&kcursor[key], 1);
        ebuf[pos] = p;
    }
    __syncthreads();

    // gather-pool: 32 groups of 16 lanes; group g owns rows g and g+32
    int g2     = t >> 4;       // 0..31
    int lane16 = t & 15;
    int r0 = g2, r1 = g2 + 32;
    vfloat4 a0 = {0.f,0.f,0.f,0.f}, a1 = {0.f,0.f,0.f,0.f};
    vfloat4 b0 = {0.f,0.f,0.f,0.f}, b1 = {0.f,0.f,0.f,0.f};
    #pragma unroll
    for (int q = 0; q < 4; q++) {
        accum_range(ebuf, kstart[q * 64 + r0], kstart[q * 64 + r0 + 1], lane16, emb16, a0, a1);
        accum_range(ebuf, kstart[q * 64 + r1], kstart[q * 64 + r1 + 1], lane16, emb16, b0, b1);
    }

    float* orow0 = out + ((size_t)bin * RPB + r0) * Dq + lane16 * 8;
    float* orow1 = out + ((size_t)bin * RPB + r1) * Dq + lane16 * 8;
    __builtin_nontemporal_store(a0, reinterpret_cast<vfloat4*>(orow0));
    __builtin_nontemporal_store(a1, reinterpret_cast<vfloat4*>(orow0) + 1);
    __builtin_nontemporal_store(b0, reinterpret_cast<vfloat4*>(orow1));
    __builtin_nontemporal_store(b1, reinterpret_cast<vfloat4*>(orow1) + 1);
}

extern "C" void kernel_launch(void* const* d_in, const int* in_sizes, int n_in,
                              void* d_out, int out_size, void* d_ws, size_t ws_size,
                              hipStream_t stream) {
    const int*   subnode_ids  = (const int*)d_in[0];
    const int*   mask_batch   = (const int*)d_in[1];
    const int*   mask_node    = (const int*)d_in[2];
    const int*   mask_subnode = (const int*)d_in[3];
    const float* mask_values  = (const float*)d_in[4];
    const float* emb_table    = (const float*)d_in[5];
    float*       out          = (float*)d_out;

    // ws layout: emb16[VOCAB*D halves, 12.86 MB] | binMem[NBLK*ENT u64, 8 MB]
    //          | offTab[NBLK*NBIN u32, 1 MB]
    unsigned short* emb16 = (unsigned short*)d_ws;
    u64* binMem = (u64*)(emb16 + (size_t)VOCABq * Dq + 64 /*align pad*/);
    unsigned* offTab = (unsigned*)(binMem + (size_t)NBLK * ENT);

    cast_kernel<<<(NQUAD + 255) / 256, 256, 0, stream>>>(emb_table, emb16);
    bin_kernel<<<NBLK, TPB, 0, stream>>>(
        subnode_ids, mask_batch, mask_node, mask_subnode, mask_values,
        binMem, offTab);
    pool_kernel<<<NBIN, TPB, 0, stream>>>(emb16, binMem, offTab, out);
}

// Round 7
// 133.448 us; speedup vs baseline: 1.0389x; 1.0179x over previous
//
#include <hip/hip_runtime.h>
#include <hip/hip_fp16.h>

#define Bq 16
#define Nq 2048
#define Sq 4096
#define Dq 128
#define VOCABq 50257
#define NNZq 1048576
#define ROWS (Bq * Nq)   // 32768
#define NBIN 512         // bins of 64 rows
#define RPB 64           // rows per bin
#define BTPB 1024        // bin kernel threads
#define BEPT 4           // bin entries per thread
#define ENT (BTPB * BEPT)       // 4096 entries per bin-block
#define NBLK (NNZq / ENT)       // 256 bin blocks
#define PTPB 512         // pool threads
#define NKEY 256         // pool sort keys: 4 token-quarters x 64 rows
#define EBUF 2560        // per-bin entry cap (mean 2048, sd ~45 -> +11 sigma)
#define NQUAD ((VOCABq * Dq) / 4)   // 1,608,224

typedef unsigned long long u64;
typedef u64 u64x2 __attribute__((ext_vector_type(2)));
typedef float vfloat4 __attribute__((ext_vector_type(4)));
typedef unsigned short vushort4 __attribute__((ext_vector_type(4)));
typedef unsigned short vushort8 __attribute__((ext_vector_type(8)));

// exclusive prefix over blockDim values (one per thread); NW = waves/block
template <int NW>
__device__ __forceinline__ int scan_block(int val, int t, int* waveSum) {
    int lane = t & 63, wid = t >> 6;
    int vi = val;
    #pragma unroll
    for (int d = 1; d < 64; d <<= 1) {
        int w = __shfl_up(vi, d, 64);
        if (lane >= d) vi += w;
    }
    if (lane == 63) waveSum[wid] = vi;
    __syncthreads();
    if (t == 0) {
        int s = 0;
        #pragma unroll
        for (int w = 0; w < NW; w++) { int x = waveSum[w]; waveSum[w] = s; s += x; }
    }
    __syncthreads();
    return vi - val + waveSum[wid];
}

#define FMA8(e_, v_, A0_, A1_)                                   \
    A0_.x += __half2float(__ushort_as_half(e_[0])) * v_;         \
    A0_.y += __half2float(__ushort_as_half(e_[1])) * v_;         \
    A0_.z += __half2float(__ushort_as_half(e_[2])) * v_;         \
    A0_.w += __half2float(__ushort_as_half(e_[3])) * v_;         \
    A1_.x += __half2float(__ushort_as_half(e_[4])) * v_;         \
    A1_.y += __half2float(__ushort_as_half(e_[5])) * v_;         \
    A1_.z += __half2float(__ushort_as_half(e_[6])) * v_;         \
    A1_.w += __half2float(__ushort_as_half(e_[7])) * v_;

// accumulate ebuf[k..s1): full 8-chunks pipelined, then ONE predicated 8-chunk
// tail (static indexing; loads issue in parallel instead of the old serial path)
__device__ __forceinline__ void accum_range(
    const u64* ebuf, int k, int s1, int lane16,
    const unsigned short* __restrict__ emb16, vfloat4& A0, vfloat4& A1)
{
    for (; k + 8 <= s1; k += 8) {
        int tk[8]; float vv[8];
        #pragma unroll
        for (int u = 0; u < 8; u++) {
            u64 pk = ebuf[k + u];
            tk[u] = (int)(pk & 0xFFFF);
            vv[u] = __int_as_float((int)(pk >> 32));
        }
        vushort8 e[8];
        #pragma unroll
        for (int u = 0; u < 8; u++)
            e[u] = reinterpret_cast<const vushort8*>(emb16 + (size_t)tk[u] * Dq)[lane16];
        #pragma unroll
        for (int u = 0; u < 8; u++) { FMA8(e[u], vv[u], A0, A1) }
    }
    int rem = s1 - k;          // 0..7, uniform within the 16-lane group
    if (rem > 0) {
        int tk[8]; float vv[8]; vushort8 e[8];
        #pragma unroll
        for (int u = 0; u < 8; u++) if (u < rem) {
            u64 pk = ebuf[k + u];
            tk[u] = (int)(pk & 0xFFFF);
            vv[u] = __int_as_float((int)(pk >> 32));
        }
        #pragma unroll
        for (int u = 0; u < 8; u++) if (u < rem)
            e[u] = reinterpret_cast<const vushort8*>(emb16 + (size_t)tk[u] * Dq)[lane16];
        #pragma unroll
        for (int u = 0; u < 8; u++) if (u < rem) { FMA8(e[u], vv[u], A0, A1) }
    }
}

// two ranges interleaved: 16 row-gathers in flight per thread (2x MLP vs serial)
__device__ __forceinline__ void accum_pair(
    const u64* ebuf, int ka, int s1a, int kb, int s1b, int lane16,
    const unsigned short* __restrict__ emb16,
    vfloat4& A0, vfloat4& A1, vfloat4& B0, vfloat4& B1)
{
    while (ka + 8 <= s1a && kb + 8 <= s1b) {
        int tk[16]; float vv[16];
        #pragma unroll
        for (int u = 0; u < 8; u++) {
            u64 pa = ebuf[ka + u];
            tk[u]     = (int)(pa & 0xFFFF);
            vv[u]     = __int_as_float((int)(pa >> 32));
            u64 pb = ebuf[kb + u];
            tk[u + 8] = (int)(pb & 0xFFFF);
            vv[u + 8] = __int_as_float((int)(pb >> 32));
        }
        vushort8 e[16];
        #pragma unroll
        for (int u = 0; u < 16; u++)
            e[u] = reinterpret_cast<const vushort8*>(emb16 + (size_t)tk[u] * Dq)[lane16];
        #pragma unroll
        for (int u = 0; u < 8; u++) { FMA8(e[u], vv[u], A0, A1) }
        #pragma unroll
        for (int u = 0; u < 8; u++) { FMA8(e[u + 8], vv[u + 8], B0, B1) }
        ka += 8; kb += 8;
    }
    accum_range(ebuf, ka, s1a, lane16, emb16, A0, A1);
    accum_range(ebuf, kb, s1b, lane16, emb16, B0, B1);
}

// ---------- Pass 0: cast emb table fp32 -> fp16 (rows 512B -> 256B) ----------
__global__ __launch_bounds__(256) void cast_kernel(
    const float* __restrict__ emb, unsigned short* __restrict__ emb16)
{
    int i = blockIdx.x * 256 + threadIdx.x;
    if (i >= NQUAD) return;
    vfloat4 f = reinterpret_cast<const vfloat4*>(emb)[i];
    vushort4 h;
    h.x = __half_as_ushort(__float2half_rn(f.x));
    h.y = __half_as_ushort(__float2half_rn(f.y));
    h.z = __half_as_ushort(__float2half_rn(f.z));
    h.w = __half_as_ushort(__float2half_rn(f.w));
    __builtin_nontemporal_store(h, reinterpret_cast<vushort4*>(emb16) + i);
}

// ---------- Pass A: per-block bin sort -> private contiguous segment ----------
// 4096 entries/block (2x R6): scan/offTab/barrier machinery amortized over 2x
// entries; per-(block,bin) slices now mean 8 entries = one full 64B line.
__global__ __launch_bounds__(BTPB) void bin_kernel(
    const int* __restrict__ subnode_ids,   // [B,S]
    const int* __restrict__ mb,            // [NNZ]
    const int* __restrict__ mn,            // [NNZ]
    const int* __restrict__ ms,            // [NNZ]
    const float* __restrict__ mv,          // [NNZ]
    u64* __restrict__ binMem,              // [NBLK][ENT] sorted-by-bin blobs
    unsigned* __restrict__ offTab)         // [NBLK][NBIN] off | cnt<<16
{
    __shared__ int hist[NBIN];             // 2 KB
    __shared__ int lstart[NBIN];           // 2 KB
    __shared__ int waveSum[BTPB / 64];
    __shared__ u64 spk[ENT] __attribute__((aligned(16)));   // 32 KB sorted entries

    int t   = threadIdx.x;
    int blk = blockIdx.x;

    if (t < NBIN) hist[t] = 0;
    __syncthreads();

    int base = blk * ENT;
    int g[BEPT], rank[BEPT];
    u64 pk[BEPT];
    #pragma unroll
    for (int k = 0; k < BEPT; k++) {       // coalesced NT index loads + L2 token gather
        int i   = base + k * BTPB + t;
        int b   = __builtin_nontemporal_load(mb + i);
        int row = b * Nq + __builtin_nontemporal_load(mn + i);
        int s   = __builtin_nontemporal_load(ms + i);
        float v = __builtin_nontemporal_load(mv + i);
        int tok = subnode_ids[b * Sq + s];
        g[k]  = row >> 6;                  // bin of 64 rows
        pk[k] = ((u64)(unsigned)__float_as_int(v) << 32)
              | ((u64)(row & 63) << 16)
              | (unsigned)tok;             // tok < 65536 fits 16 bits
        rank[k] = atomicAdd(&hist[g[k]], 1);
    }
    __syncthreads();

    int cnt = (t < NBIN) ? hist[t] : 0;
    int ex  = scan_block<BTPB / 64>(cnt, t, waveSum);
    if (t < NBIN) {
        lstart[t] = ex;
        offTab[blk * NBIN + t] = (unsigned)ex | ((unsigned)cnt << 16);  // coalesced
    }
    __syncthreads();

    #pragma unroll
    for (int k = 0; k < BEPT; k++)
        spk[lstart[g[k]] + rank[k]] = pk[k];
    __syncthreads();

    // contiguous vectorized blob write-out (16B stores)
    const u64x2* s2 = reinterpret_cast<const u64x2*>(spk);
    u64x2* d2 = reinterpret_cast<u64x2*>(binMem + (size_t)blk * ENT);
    #pragma unroll
    for (int p = t; p < ENT / 2; p += BTPB) d2[p] = s2[p];
}

// ---------- Pass B: gather slices -> in-LDS key sort -> phased pool ----------
// Block b = bin b (64 rows). Slice copy: 2 threads per producer slice (halves
// of ~4 entries; the pair shares one 64B line). LDS-only 256-key histogram /
// scan / scatter into ebuf sorted by key = (tok>>14)<<6 | row_local. 32 groups
// x 16 lanes; group g owns rows g and g+32 with the two ranges INTERLEAVED
// (16 row-gathers in flight); 4 token-quarter phases (~3.2MB fp16 slice
// L2-resident across co-resident blocks); one NT 512B store per row.
__global__ __launch_bounds__(PTPB) void pool_kernel(
    const unsigned short* __restrict__ emb16,  // [VOCAB,D] fp16
    const u64* __restrict__ binMem,            // [NBLK][ENT]
    const unsigned* __restrict__ offTab,       // [NBLK][NBIN] off | cnt<<16
    float* __restrict__ out)                   // [ROWS,D]
{
    __shared__ u64 spk[EBUF] __attribute__((aligned(16)));   // 20 KB staged
    __shared__ u64 ebuf[EBUF];             // 20 KB key-sorted entries
    __shared__ int waveSum[PTPB / 64];
    __shared__ int khist[NKEY];            // 1 KB
    __shared__ int kstart[NKEY + 1];
    __shared__ int kcursor[NKEY];
    __shared__ int nTot;

    int t   = threadIdx.x;
    int bin = blockIdx.x;

    // slice meta: threads 2s,2s+1 own the two halves of producer block s's slice
    int slice = t >> 1, half = t & 1;
    unsigned m = offTab[slice * NBIN + bin];
    int soff = (int)(m & 0xFFFFu);
    int c    = (int)(m >> 16);
    int c0   = (c + 1) >> 1;
    int myoff = soff + (half ? c0 : 0);
    int myc   = half ? (c - c0) : c0;
    int db = scan_block<PTPB / 64>(myc, t, waveSum);
    if (t == PTPB - 1) nTot = db + myc;
    if (db >= EBUF) myc = 0;
    else if (db + myc > EBUF) myc = EBUF - db;       // paranoia clamp

    {   // cooperative slice copy (contiguous run per thread)
        const u64* src = binMem + (size_t)slice * ENT + myoff;
        for (int i = 0; i < myc; i++) spk[db + i] = src[i];
    }
    if (t < NKEY) khist[t] = 0;
    __syncthreads();

    int n = nTot < EBUF ? nTot : EBUF;

    // 256-key histogram from staged LDS
    for (int e = t; e < n; e += PTPB) {
        u64 p = spk[e];
        int key = (((int)(p & 0xFFFF)) >> 14 << 6) | ((int)(p >> 16) & 63);
        atomicAdd(&khist[key], 1);
    }
    __syncthreads();

    int kval = (t < NKEY) ? khist[t] : 0;
    int kex  = scan_block<PTPB / 64>(kval, t, waveSum);
    if (t < NKEY) {
        kstart[t]  = kex;
        kcursor[t] = kex;
        if (t == NKEY - 1) kstart[NKEY] = kex + kval;
    }
    __syncthreads();

    // scatter into key-sorted ebuf
    for (int e = t; e < n; e += PTPB) {
        u64 p = spk[e];
        int key = (((int)(p & 0xFFFF)) >> 14 << 6) | ((int)(p >> 16) & 63);
        int pos = atomicAdd(&kcursor[key], 1);
        ebuf[pos] = p;
    }
    __syncthreads();

    // gather-pool: 32 groups of 16 lanes; group g owns rows g and g+32
    int g2     = t >> 4;       // 0..31
    int lane16 = t & 15;
    int r0 = g2, r1 = g2 + 32;
    vfloat4 a0 = {0.f,0.f,0.f,0.f}, a1 = {0.f,0.f,0.f,0.f};
    vfloat4 b0 = {0.f,0.f,0.f,0.f}, b1 = {0.f,0.f,0.f,0.f};
    #pragma unroll
    for (int q = 0; q < 4; q++) {
        accum_pair(ebuf,
                   kstart[q * 64 + r0], kstart[q * 64 + r0 + 1],
                   kstart[q * 64 + r1], kstart[q * 64 + r1 + 1],
                   lane16, emb16, a0, a1, b0, b1);
    }

    float* orow0 = out + ((size_t)bin * RPB + r0) * Dq + lane16 * 8;
    float* orow1 = out + ((size_t)bin * RPB + r1) * Dq + lane16 * 8;
    __builtin_nontemporal_store(a0, reinterpret_cast<vfloat4*>(orow0));
    __builtin_nontemporal_store(a1, reinterpret_cast<vfloat4*>(orow0) + 1);
    __builtin_nontemporal_store(b0, reinterpret_cast<vfloat4*>(orow1));
    __builtin_nontemporal_store(b1, reinterpret_cast<vfloat4*>(orow1) + 1);
}

extern "C" void kernel_launch(void* const* d_in, const int* in_sizes, int n_in,
                              void* d_out, int out_size, void* d_ws, size_t ws_size,
                              hipStream_t stream) {
    const int*   subnode_ids  = (const int*)d_in[0];
    const int*   mask_batch   = (const int*)d_in[1];
    const int*   mask_node    = (const int*)d_in[2];
    const int*   mask_subnode = (const int*)d_in[3];
    const float* mask_values  = (const float*)d_in[4];
    const float* emb_table    = (const float*)d_in[5];
    float*       out          = (float*)d_out;

    // ws layout: emb16[VOCAB*D halves, 12.86 MB] | binMem[NBLK*ENT u64, 8 MB]
    //          | offTab[NBLK*NBIN u32, 512 KB]
    unsigned short* emb16 = (unsigned short*)d_ws;
    u64* binMem = (u64*)(emb16 + (size_t)VOCABq * Dq + 64 /*align pad*/);
    unsigned* offTab = (unsigned*)(binMem + (size_t)NBLK * ENT);

    cast_kernel<<<(NQUAD + 255) / 256, 256, 0, stream>>>(emb_table, emb16);
    bin_kernel<<<NBLK, BTPB, 0, stream>>>(
        subnode_ids, mask_batch, mask_node, mask_subnode, mask_values,
        binMem, offTab);
    pool_kernel<<<NBIN, PTPB, 0, stream>>>(emb16, binMem, offTab, out);
}